// Round 4
// baseline (1339.621 us; speedup 1.0000x reference)
//
#include <hip/hip_runtime.h>
#include <cmath>
#include <cstddef>

#define N_NODES 50000
#define N_PAD   50048
#define E_EDGES 640000
#define HDIM 128
#define COUT 64
#define NLAYERS 16
#define ALPHA_C 0.1f
#define LAMDA_C 0.5f
#define SCAN_BLKS 196   // ceil(50000/256)
#define NXCC 8

typedef __attribute__((ext_vector_type(8))) short short8;
typedef __attribute__((ext_vector_type(4))) float f32x4;

__device__ __forceinline__ float bf2f(ushort u) {
    union { unsigned u; float f; } x; x.u = ((unsigned)u) << 16; return x.f;
}
__device__ __forceinline__ ushort f2bf(float f) {
    union { float f; unsigned u; } x; x.f = f;
    unsigned r = x.u + 0x7FFFu + ((x.u >> 16) & 1u);
    return (ushort)(r >> 16);
}
__device__ __forceinline__ int xcc_id() {
    int x;
    asm volatile("s_getreg_b32 %0, hwreg(HW_REG_XCC_ID)" : "=s"(x));
    return x & (NXCC - 1);
}

// ---------------- graph setup ----------------

// 4 edges/thread; XCD-local (workgroup-scope) atomics into per-XCC copies.
// rank[e] = intra-(xcc,dest) arrival order | xcc<<24
__global__ __launch_bounds__(256) void k_edge(const int* __restrict__ ei,
                                              const float* __restrict__ ew,
                                              float* __restrict__ degC,
                                              int* __restrict__ cntC,
                                              int* __restrict__ rank) {
    const int xcc = xcc_id();
    float* deg = degC + (size_t)xcc * N_NODES;
    int* cnt = cntC + (size_t)xcc * N_NODES;
    int t = blockIdx.x * 256 + threadIdx.x;
    int e0 = t * 4;
    if (e0 >= E_EDGES) return;
    int4 r = *(const int4*)&ei[e0];
    int4 c = *(const int4*)&ei[E_EDGES + e0];
    float4 w = *(const float4*)&ew[e0];
    __hip_atomic_fetch_add(&deg[r.x], w.x, __ATOMIC_RELAXED, __HIP_MEMORY_SCOPE_WORKGROUP);
    __hip_atomic_fetch_add(&deg[r.y], w.y, __ATOMIC_RELAXED, __HIP_MEMORY_SCOPE_WORKGROUP);
    __hip_atomic_fetch_add(&deg[r.z], w.z, __ATOMIC_RELAXED, __HIP_MEMORY_SCOPE_WORKGROUP);
    __hip_atomic_fetch_add(&deg[r.w], w.w, __ATOMIC_RELAXED, __HIP_MEMORY_SCOPE_WORKGROUP);
    int4 rk;
    rk.x = __hip_atomic_fetch_add(&cnt[c.x], 1, __ATOMIC_RELAXED, __HIP_MEMORY_SCOPE_WORKGROUP);
    rk.y = __hip_atomic_fetch_add(&cnt[c.y], 1, __ATOMIC_RELAXED, __HIP_MEMORY_SCOPE_WORKGROUP);
    rk.z = __hip_atomic_fetch_add(&cnt[c.z], 1, __ATOMIC_RELAXED, __HIP_MEMORY_SCOPE_WORKGROUP);
    rk.w = __hip_atomic_fetch_add(&cnt[c.w], 1, __ATOMIC_RELAXED, __HIP_MEMORY_SCOPE_WORKGROUP);
    const int tag = xcc << 24;
    rk.x |= tag; rk.y |= tag; rk.z |= tag; rk.w |= tag;
    *(int4*)&rank[e0] = rk;
}

// merge 8 copies: total cnt, per-XCC prefix offsets (in place), dinv = 1/sqrt(1+deg)
__global__ __launch_bounds__(256) void k_merge(float* __restrict__ degC,
                                               int* __restrict__ cntC,
                                               int* __restrict__ cnt,
                                               float* __restrict__ dinv) {
    int i = blockIdx.x * 256 + threadIdx.x;
    if (i >= N_PAD) return;
    if (i < N_NODES) {
        int run = 0;
        float d = 1.0f;
#pragma unroll
        for (int x = 0; x < NXCC; ++x) {
            int c = cntC[(size_t)x * N_NODES + i];
            cntC[(size_t)x * N_NODES + i] = run;
            run += c;
            d += degC[(size_t)x * N_NODES + i];
        }
        cnt[i] = run;
        dinv[i] = 1.0f / sqrtf(d);
    } else {
        dinv[i] = 1.0f;
    }
}

__global__ __launch_bounds__(256) void k_scan1(const int* __restrict__ cnt,
                                               int* ptrTmp, int* bsum) {
    __shared__ int s[256];
    int t = threadIdx.x;
    int i = blockIdx.x * 256 + t;
    int v = (i < N_NODES) ? cnt[i] : 0;
    s[t] = v; __syncthreads();
    for (int off = 1; off < 256; off <<= 1) {
        int x = s[t]; int y = (t >= off) ? s[t - off] : 0;
        __syncthreads();
        s[t] = x + y; __syncthreads();
    }
    if (i < N_NODES) ptrTmp[i] = s[t] - v;
    if (t == 255) bsum[blockIdx.x] = s[255];
}

__global__ __launch_bounds__(256) void k_scan2(const int* __restrict__ bsum, int* boff) {
    __shared__ int s[256];
    int t = threadIdx.x;
    int v = (t < SCAN_BLKS) ? bsum[t] : 0;
    s[t] = v; __syncthreads();
    for (int off = 1; off < 256; off <<= 1) {
        int x = s[t]; int y = (t >= off) ? s[t - off] : 0;
        __syncthreads();
        s[t] = x + y; __syncthreads();
    }
    if (t < SCAN_BLKS) boff[t] = s[t] - v;
}

__global__ __launch_bounds__(256) void k_scan3(const int* __restrict__ ptrTmp,
                                               const int* __restrict__ boff, int* ptr) {
    int i = blockIdx.x * 256 + threadIdx.x;
    if (i < N_NODES) ptr[i] = ptrTmp[i] + boff[blockIdx.x];
    if (i == 0) ptr[N_NODES] = E_EDGES;
}

// atomic-free scatter: pos = ptr[c] + off[xcc][c] + rank
__global__ __launch_bounds__(256) void k_scatter(const int* __restrict__ ei,
                                                 const float* __restrict__ ew,
                                                 const float* __restrict__ dinv,
                                                 const int* __restrict__ ptr,
                                                 const int* __restrict__ offC,
                                                 const int* __restrict__ rank,
                                                 int2* __restrict__ spack) {
    int t = blockIdx.x * 256 + threadIdx.x;
    int e0 = t * 4;
    if (e0 >= E_EDGES) return;
    int4 r = *(const int4*)&ei[e0];
    int4 c = *(const int4*)&ei[E_EDGES + e0];
    float4 w = *(const float4*)&ew[e0];
    int4 rk = *(const int4*)&rank[e0];
#pragma unroll
    for (int j = 0; j < 4; ++j) {
        int rr = (j == 0) ? r.x : (j == 1) ? r.y : (j == 2) ? r.z : r.w;
        int cc = (j == 0) ? c.x : (j == 1) ? c.y : (j == 2) ? c.z : c.w;
        float wwv = (j == 0) ? w.x : (j == 1) ? w.y : (j == 2) ? w.z : w.w;
        int rkj = (j == 0) ? rk.x : (j == 1) ? rk.y : (j == 2) ? rk.z : rk.w;
        int xcc = ((unsigned)rkj) >> 24;
        int rnk = rkj & 0xFFFFFF;
        int pos = ptr[cc] + offC[(size_t)xcc * N_NODES + cc] + rnk;
        float nm = dinv[rr] * wwv * dinv[cc];
        int2 m; m.x = rr; m.y = __float_as_int(nm);
        spack[pos] = m;
    }
}

// ---------------- weight convert + transpose + residual fold ----------------
// layer weights become W' = beta*W + diagC*I, stored bf16 transposed [C][R]

__global__ __launch_bounds__(256) void k_convert_w(
    const float* __restrict__ w_in, const float* __restrict__ ws1,
    const float* __restrict__ ws2, const float* __restrict__ w_out,
    ushort* wt_in, ushort* wt1, ushort* wt2, ushort* wt_out) {
    __shared__ float tile[128][129];
    int b = blockIdx.x;
    const float* src; ushort* dst; int R = 128, C = 128;
    float scale = 1.f, diag = 0.f;
    if (b == 0) { src = w_in; dst = wt_in; }
    else if (b <= 16) {
        int i = b - 1;
        float beta = logf(LAMDA_C / (float)(i + 1) + 1.0f);
        scale = beta; diag = (1.f - beta) * (1.f - ALPHA_C);
        src = ws1 + (size_t)i * 16384; dst = wt1 + (size_t)i * 16384;
    } else if (b <= 32) {
        int i = b - 17;
        float beta = logf(LAMDA_C / (float)(i + 1) + 1.0f);
        scale = beta; diag = (1.f - beta) * ALPHA_C;
        src = ws2 + (size_t)i * 16384; dst = wt2 + (size_t)i * 16384;
    } else { src = w_out; dst = wt_out; C = 64; }
    for (int idx = threadIdx.x; idx < R * C; idx += 256) {
        int k = idx / C, n = idx % C;
        tile[k][n] = src[idx] * scale + ((k == n) ? diag : 0.f);
    }
    __syncthreads();
    for (int idx = threadIdx.x; idx < R * C; idx += 256) {
        int n = idx / R, k = idx % R;
        dst[idx] = f2bf(tile[k][n]);
    }
}

// ---------------- x convert (f32 -> bf16, zero-pad rows) ----------------

__global__ __launch_bounds__(256) void k_convert_x(const float* __restrict__ x,
                                                   ushort* __restrict__ xb) {
    int c8 = blockIdx.x * 256 + threadIdx.x;
    if (c8 >= N_PAD * (HDIM / 8)) return;
    int row = c8 / (HDIM / 8);
    short8 o;
    if (row < N_NODES) {
        const float4 f0 = *(const float4*)&x[(size_t)c8 * 8];
        const float4 f1 = *(const float4*)&x[(size_t)c8 * 8 + 4];
        o[0] = (short)f2bf(f0.x); o[1] = (short)f2bf(f0.y);
        o[2] = (short)f2bf(f0.z); o[3] = (short)f2bf(f0.w);
        o[4] = (short)f2bf(f1.x); o[5] = (short)f2bf(f1.y);
        o[6] = (short)f2bf(f1.z); o[7] = (short)f2bf(f1.w);
    } else {
        o = (short8){0, 0, 0, 0, 0, 0, 0, 0};
    }
    *(short8*)&xb[(size_t)c8 * 8] = o;
}

// ---------------- input GEMM: h = h0 = relu(xb @ W + bias) ----------------

__global__ __launch_bounds__(256) void k_gemm_in(
    const ushort* __restrict__ A, const ushort* __restrict__ W,
    const float* __restrict__ bias, ushort* __restrict__ O0, ushort* __restrict__ O1) {
    const int tid = threadIdx.x;
    const int wid = tid >> 6, l = tid & 63;
    const int wm = wid >> 1, wn = wid & 1;
    const int lr = l & 15, lk = l >> 4;
    const int row0 = blockIdx.x * 128 + wm * 64;
    const int col0 = wn * 64;

    short8 a[4][4], b[4][4];
#pragma unroll
    for (int m = 0; m < 4; ++m)
#pragma unroll
        for (int k = 0; k < 4; ++k)
            a[m][k] = *(const short8*)&A[(size_t)(row0 + m * 16 + lr) * HDIM + k * 32 + lk * 8];
#pragma unroll
    for (int n = 0; n < 4; ++n)
#pragma unroll
        for (int k = 0; k < 4; ++k)
            b[n][k] = *(const short8*)&W[(size_t)(col0 + n * 16 + lr) * HDIM + k * 32 + lk * 8];

    f32x4 acc[4][4];
#pragma unroll
    for (int m = 0; m < 4; ++m)
#pragma unroll
        for (int n = 0; n < 4; ++n) acc[m][n] = (f32x4){0.f, 0.f, 0.f, 0.f};
#pragma unroll
    for (int k = 0; k < 4; ++k)
#pragma unroll
        for (int m = 0; m < 4; ++m)
#pragma unroll
            for (int n = 0; n < 4; ++n)
                acc[m][n] = __builtin_amdgcn_mfma_f32_16x16x32_bf16(a[m][k], b[n][k], acc[m][n], 0, 0, 0);

    float bv[4];
#pragma unroll
    for (int n = 0; n < 4; ++n) bv[n] = bias[col0 + n * 16 + lr];
#pragma unroll
    for (int m = 0; m < 4; ++m) {
        const int rb = row0 + m * 16 + lk * 4;
#pragma unroll
        for (int j = 0; j < 4; ++j) {
            const size_t ro = (size_t)(rb + j) * HDIM;
#pragma unroll
            for (int n = 0; n < 4; ++n) {
                const int c = col0 + n * 16 + lr;
                float v = fmaxf(acc[m][n][j] + bv[n], 0.f);
                ushort u = f2bf(v);
                O0[ro + c] = u;
                O1[ro + c] = u;
            }
        }
    }
}

// ---------------- support GEMM: O = A @ W' (residual folded) ----------------

__global__ __launch_bounds__(256) void k_gemm1(
    const ushort* __restrict__ A, const ushort* __restrict__ W,
    ushort* __restrict__ O) {
    const int tid = threadIdx.x;
    const int wid = tid >> 6, l = tid & 63;
    const int wm = wid >> 1, wn = wid & 1;
    const int lr = l & 15, lk = l >> 4;
    const int row0 = blockIdx.x * 128 + wm * 64;
    const int col0 = wn * 64;

    short8 a[4][4], b[4][4];
#pragma unroll
    for (int m = 0; m < 4; ++m)
#pragma unroll
        for (int k = 0; k < 4; ++k)
            a[m][k] = *(const short8*)&A[(size_t)(row0 + m * 16 + lr) * HDIM + k * 32 + lk * 8];
#pragma unroll
    for (int n = 0; n < 4; ++n)
#pragma unroll
        for (int k = 0; k < 4; ++k)
            b[n][k] = *(const short8*)&W[(size_t)(col0 + n * 16 + lr) * HDIM + k * 32 + lk * 8];

    f32x4 acc[4][4];
#pragma unroll
    for (int m = 0; m < 4; ++m)
#pragma unroll
        for (int n = 0; n < 4; ++n) acc[m][n] = (f32x4){0.f, 0.f, 0.f, 0.f};
#pragma unroll
    for (int k = 0; k < 4; ++k)
#pragma unroll
        for (int m = 0; m < 4; ++m)
#pragma unroll
            for (int n = 0; n < 4; ++n)
                acc[m][n] = __builtin_amdgcn_mfma_f32_16x16x32_bf16(a[m][k], b[n][k], acc[m][n], 0, 0, 0);

#pragma unroll
    for (int m = 0; m < 4; ++m) {
        const int rb = row0 + m * 16 + lk * 4;
#pragma unroll
        for (int j = 0; j < 4; ++j) {
            const size_t ro = (size_t)(rb + j) * HDIM;
#pragma unroll
            for (int n = 0; n < 4; ++n)
                O[ro + col0 + n * 16 + lr] = f2bf(acc[m][n][j]);
        }
    }
}

// ---------------- fused aggregate + init-GEMM + relu ----------------
// block: 64 nodes, 4 waves. Phase A: gather-aggregate (+self) -> LDS f32.
// Phase B: init = h0_blk @ W2' via MFMA; h = relu(agg + init).

__global__ __launch_bounds__(256) void k_agg_gemm(
    const ushort* __restrict__ support, const ushort* __restrict__ h0,
    const ushort* __restrict__ W2t, const float* __restrict__ dinv,
    const int* __restrict__ ptr, const int2* __restrict__ spack,
    ushort* __restrict__ hout) {
    __shared__ float agg[64][132];
    const int tid = threadIdx.x;
    const int w = tid >> 6, l = tid & 63;
    const int q = l >> 4, i = l & 15;
    const int nodebase = blockIdx.x * 64;

    // ---- phase A ----
    for (int t = 0; t < 16; ++t) {
        int v = nodebase + w * 16 + t;
        int beg = 0, end = 0;
        if (v < N_NODES) { beg = ptr[v]; end = ptr[v + 1]; }
        float acc[8];
#pragma unroll
        for (int d = 0; d < 8; ++d) acc[d] = 0.f;
        for (int base = beg; base < end; base += 64) {
            int cnt = end - base; if (cnt > 64) cnt = 64;
            int2 meta = make_int2(0, 0);
            if (base + l < end) meta = spack[base + l];
            for (int j = 0; j < cnt; j += 4) {
                int idx = j + q;
                int rr = __shfl(meta.x, idx);
                int nb = __shfl(meta.y, idx);
                if (idx < cnt) {
                    float nn = __int_as_float(nb);
                    short8 sv = *(const short8*)&support[(size_t)rr * HDIM + i * 8];
#pragma unroll
                    for (int d = 0; d < 8; ++d)
                        acc[d] = fmaf(nn, bf2f((ushort)sv[d]), acc[d]);
                }
            }
        }
#pragma unroll
        for (int d = 0; d < 8; ++d) {
            acc[d] += __shfl_xor(acc[d], 16);
            acc[d] += __shfl_xor(acc[d], 32);
        }
        if (q == 0) {
            float dv = dinv[v];
            float dv2 = dv * dv;
            short8 s0 = *(const short8*)&support[(size_t)v * HDIM + i * 8];
            float o[8];
#pragma unroll
            for (int d = 0; d < 8; ++d) o[d] = acc[d] + dv2 * bf2f((ushort)s0[d]);
            *(float4*)&agg[w * 16 + t][i * 8] = *(float4*)&o[0];
            *(float4*)&agg[w * 16 + t][i * 8 + 4] = *(float4*)&o[4];
        }
    }
    __syncthreads();

    // ---- phase B ----
    const int lr = i, lk = q;
    const int rowbase = nodebase + w * 16;
    short8 a[4];
#pragma unroll
    for (int k = 0; k < 4; ++k)
        a[k] = *(const short8*)&h0[(size_t)(rowbase + lr) * HDIM + k * 32 + lk * 8];
#pragma unroll
    for (int n = 0; n < 8; ++n) {
        short8 b[4];
#pragma unroll
        for (int k = 0; k < 4; ++k)
            b[k] = *(const short8*)&W2t[(size_t)(n * 16 + lr) * HDIM + k * 32 + lk * 8];
        f32x4 acc4 = (f32x4){0.f, 0.f, 0.f, 0.f};
#pragma unroll
        for (int k = 0; k < 4; ++k)
            acc4 = __builtin_amdgcn_mfma_f32_16x16x32_bf16(a[k], b[k], acc4, 0, 0, 0);
#pragma unroll
        for (int j = 0; j < 4; ++j) {
            int row_o = lk * 4 + j;
            float v = acc4[j] + agg[w * 16 + row_o][n * 16 + lr];
            hout[(size_t)(rowbase + row_o) * HDIM + n * 16 + lr] = f2bf(fmaxf(v, 0.f));
        }
    }
}

// ---------------- output GEMM + fused bias + log_softmax ----------------

__global__ __launch_bounds__(256) void k_gemm_out(
    const ushort* __restrict__ A, const ushort* __restrict__ W,
    const float* __restrict__ bias, float* __restrict__ out) {
    const int tid = threadIdx.x;
    const int wid = tid >> 6, l = tid & 63;
    const int lr = l & 15, lk = l >> 4;
    const int row0 = blockIdx.x * 128 + wid * 32;

    short8 a[2][4], b[4][4];
#pragma unroll
    for (int m = 0; m < 2; ++m)
#pragma unroll
        for (int k = 0; k < 4; ++k)
            a[m][k] = *(const short8*)&A[(size_t)(row0 + m * 16 + lr) * HDIM + k * 32 + lk * 8];
#pragma unroll
    for (int n = 0; n < 4; ++n)
#pragma unroll
        for (int k = 0; k < 4; ++k)
            b[n][k] = *(const short8*)&W[(size_t)(n * 16 + lr) * HDIM + k * 32 + lk * 8];

    f32x4 acc[2][4];
#pragma unroll
    for (int m = 0; m < 2; ++m)
#pragma unroll
        for (int n = 0; n < 4; ++n) acc[m][n] = (f32x4){0.f, 0.f, 0.f, 0.f};
#pragma unroll
    for (int k = 0; k < 4; ++k)
#pragma unroll
        for (int m = 0; m < 2; ++m)
#pragma unroll
            for (int n = 0; n < 4; ++n)
                acc[m][n] = __builtin_amdgcn_mfma_f32_16x16x32_bf16(a[m][k], b[n][k], acc[m][n], 0, 0, 0);

    float bv[4];
#pragma unroll
    for (int n = 0; n < 4; ++n) bv[n] = bias[n * 16 + lr];

#pragma unroll
    for (int m = 0; m < 2; ++m) {
#pragma unroll
        for (int j = 0; j < 4; ++j) {
            float z[4];
#pragma unroll
            for (int n = 0; n < 4; ++n) z[n] = acc[m][n][j] + bv[n];
            float mx = fmaxf(fmaxf(z[0], z[1]), fmaxf(z[2], z[3]));
#pragma unroll
            for (int off = 1; off < 16; off <<= 1) mx = fmaxf(mx, __shfl_xor(mx, off));
            float s = 0.f;
#pragma unroll
            for (int n = 0; n < 4; ++n) s += expf(z[n] - mx);
#pragma unroll
            for (int off = 1; off < 16; off <<= 1) s += __shfl_xor(s, off);
            float lg = mx + logf(s);
            int r = row0 + m * 16 + lk * 4 + j;
            if (r < N_NODES) {
#pragma unroll
                for (int n = 0; n < 4; ++n)
                    out[(size_t)r * COUT + n * 16 + lr] = z[n] - lg;
            }
        }
    }
}

// ---------------- launch ----------------

extern "C" void kernel_launch(void* const* d_in, const int* in_sizes, int n_in,
                              void* d_out, int out_size, void* d_ws, size_t ws_size,
                              hipStream_t stream) {
    const float* x = (const float*)d_in[0];
    const int* ei = (const int*)d_in[1];
    const float* ew = (const float*)d_in[2];
    const float* w_in = (const float*)d_in[3];
    const float* b_in = (const float*)d_in[4];
    const float* ws1 = (const float*)d_in[5];
    const float* ws2 = (const float*)d_in[6];
    const float* w_out = (const float*)d_in[7];
    const float* b_out = (const float*)d_in[8];
    float* out = (float*)d_out;

    char* p = (char*)d_ws;
    auto alloc = [&](size_t bytes) {
        void* r = (void*)p;
        p += (bytes + 255) & ~(size_t)255;
        return r;
    };
    float* degC = (float*)alloc((size_t)NXCC * N_NODES * 4);
    int* cntC = (int*)alloc((size_t)NXCC * N_NODES * 4);
    int* cnt = (int*)alloc(N_NODES * 4);
    int* ptrTmp = (int*)alloc(N_NODES * 4);
    int* bsum = (int*)alloc(256 * 4);
    int* boff = (int*)alloc(256 * 4);
    int* ptr = (int*)alloc((N_NODES + 1) * 4);
    float* dinv = (float*)alloc(N_PAD * 4);
    int* rank = (int*)alloc((size_t)E_EDGES * 4);
    int2* spack = (int2*)alloc((size_t)E_EDGES * 8);
    ushort* xb = (ushort*)alloc((size_t)N_PAD * HDIM * 2);
    ushort* h = (ushort*)alloc((size_t)N_PAD * HDIM * 2);
    ushort* h0 = (ushort*)alloc((size_t)N_PAD * HDIM * 2);
    ushort* support = (ushort*)alloc((size_t)N_PAD * HDIM * 2);
    ushort* wt_in = (ushort*)alloc(128 * 128 * 2);
    ushort* wt1 = (ushort*)alloc((size_t)NLAYERS * 128 * 128 * 2);
    ushort* wt2 = (ushort*)alloc((size_t)NLAYERS * 128 * 128 * 2);
    ushort* wt_out = (ushort*)alloc(64 * 128 * 2);

    hipMemsetAsync(degC, 0, (size_t)NXCC * N_NODES * 4, stream);
    hipMemsetAsync(cntC, 0, (size_t)NXCC * N_NODES * 4, stream);

    const int ge4 = (E_EDGES / 4 + 255) / 256;  // 625
    k_edge<<<ge4, 256, 0, stream>>>(ei, ew, degC, cntC, rank);
    k_merge<<<SCAN_BLKS, 256, 0, stream>>>(degC, cntC, cnt, dinv);
    k_scan1<<<SCAN_BLKS, 256, 0, stream>>>(cnt, ptrTmp, bsum);
    k_scan2<<<1, 256, 0, stream>>>(bsum, boff);
    k_scan3<<<SCAN_BLKS, 256, 0, stream>>>(ptrTmp, boff, ptr);
    k_scatter<<<ge4, 256, 0, stream>>>(ei, ew, dinv, ptr, cntC, rank, spack);

    k_convert_w<<<34, 256, 0, stream>>>(w_in, ws1, ws2, w_out, wt_in, wt1, wt2, wt_out);
    k_convert_x<<<(N_PAD * (HDIM / 8) + 255) / 256, 256, 0, stream>>>(x, xb);

    const int gb = N_PAD / 128;  // 391
    k_gemm_in<<<gb, 256, 0, stream>>>(xb, wt_in, b_in, h, h0);

    for (int i = 0; i < NLAYERS; ++i) {
        k_gemm1<<<gb, 256, 0, stream>>>(h, wt1 + (size_t)i * 16384, support);
        k_agg_gemm<<<N_PAD / 64, 256, 0, stream>>>(support, h0,
                                                   wt2 + (size_t)i * 16384,
                                                   dinv, ptr, spack, h);
    }

    k_gemm_out<<<gb, 256, 0, stream>>>(h, wt_out, b_out, out);
}